// Round 8
// baseline (268.713 us; speedup 1.0000x reference)
//
#include <hip/hip_runtime.h>
#include <hip/hip_bf16.h>

// Problem dims
#define B_ 16
#define L_ 2048
#define DF 512
#define H_ 8
#define DH 512
#define U_ 512

typedef unsigned short u16;
typedef __attribute__((ext_vector_type(8))) short bf16x8;
typedef __attribute__((ext_vector_type(4))) float f32x4;

__device__ __forceinline__ u16 f2bf(float x) {
  __hip_bfloat16 h = __float2bfloat16(x);
  u16 u;
  __builtin_memcpy(&u, &h, 2);
  return u;
}

__device__ __forceinline__ void load_lds16(const void* g, void* l) {
  __builtin_amdgcn_global_load_lds(
      (const __attribute__((address_space(1))) void*)g,
      (__attribute__((address_space(3))) void*)l, 16, 0, 0);
}

// tanh(x) = 1 - 2/(1+e^{2x}); exact at +-inf, ~1e-6 abs err.
__device__ __forceinline__ float fast_tanh2(float x) {
  float e = __expf(2.f * x);
  return 1.f - __fdividef(2.f, e + 1.f);
}

// ---------------------------------------------------------------------------
// Merged conversion kernel:
//  blocks [0, 16384): features fp32 -> bf16 [B,L,DF], 4 elems/thread
//  blocks [16384, 18432): W1 [H,DF,U] -> W1T [H,U,DF] bf16 (32x32 transpose)
// ---------------------------------------------------------------------------
__global__ __launch_bounds__(256) void convert_kernel(
    const float* __restrict__ F, u16* __restrict__ Abf,
    const float* __restrict__ W1, u16* __restrict__ W1T) {
  __shared__ float t[32][33];
  if (blockIdx.x < 16384) {
    size_t i = ((size_t)blockIdx.x * 256 + threadIdx.x) * 4;
    float4 v = *(const float4*)(F + i);
    ushort4 o;
    o.x = f2bf(v.x); o.y = f2bf(v.y); o.z = f2bf(v.z); o.w = f2bf(v.w);
    *(ushort4*)(Abf + i) = o;
  } else {
    int bid = blockIdx.x - 16384;
    int d0 = (bid & 15) * 32, u0 = ((bid >> 4) & 15) * 32, h = bid >> 8;
    const float* src = W1 + (size_t)h * DF * U_;
    u16* dst = W1T + (size_t)h * U_ * DF;
#pragma unroll
    for (int i = 0; i < 4; ++i) {
      int idx = threadIdx.x + i * 256;
      int r = idx >> 5, c = idx & 31;
      t[r][c] = src[(size_t)(d0 + r) * U_ + u0 + c];
    }
    __syncthreads();
#pragma unroll
    for (int i = 0; i < 4; ++i) {
      int idx = threadIdx.x + i * 256;
      int r = idx >> 5, c = idx & 31;  // r: u index, c: d index
      dst[(size_t)(u0 + r) * DF + d0 + c] = f2bf(t[c][r]);
    }
  }
}

// ---------------------------------------------------------------------------
// hproj split-d: partial[z,b,h,u] = sum_{d in chunk z} hidden*W2
// ---------------------------------------------------------------------------
__global__ __launch_bounds__(128) void hproj_part_kernel(
    const float* __restrict__ hidden, const float* __restrict__ W2,
    float* __restrict__ partial) {
  int h = blockIdx.x;
  int u = blockIdx.y * 128 + threadIdx.x;
  int d0 = blockIdx.z * 64;
  __shared__ float hs[B_][64];
  for (int idx = threadIdx.x; idx < B_ * 64; idx += 128) {
    int b = idx >> 6, d = idx & 63;
    hs[b][d] = hidden[(size_t)(b * H_ + h) * DH + d0 + d];
  }
  __syncthreads();
  float acc[B_];
#pragma unroll
  for (int b = 0; b < B_; b++) acc[b] = 0.f;
  const float* w2p = W2 + ((size_t)h * DH + d0) * U_ + u;
  for (int d = 0; d < 64; d++) {
    float w = w2p[(size_t)d * U_];
#pragma unroll
    for (int b = 0; b < B_; b++) acc[b] += hs[b][d] * w;
  }
#pragma unroll
  for (int b = 0; b < B_; b++)
    partial[(((size_t)blockIdx.z * B_ + b) * H_ + h) * U_ + u] = acc[b];
}

__global__ __launch_bounds__(256) void hproj_combine_kernel(
    const float* __restrict__ partial, const float* __restrict__ b1,
    const float* __restrict__ b2, float* __restrict__ c) {
  int i = blockIdx.x * 256 + threadIdx.x;  // over B*H*U
  int hu = i & (H_ * U_ - 1);
  float s = b1[hu] + b2[hu];
#pragma unroll
  for (int z = 0; z < 8; z++) s += partial[(size_t)z * B_ * H_ * U_ + i];
  c[i] = s;
}

// ---------------------------------------------------------------------------
// score kernel v8: 256(l) x 256(u, split-U) tile, BK=32, QUAD-buffered LDS
// (3-step prefetch depth covers L3 latency from within one block), simple
// 2-barrier K-loop with one counted vmcnt(12) per step, XOR-swizzled LDS,
// XCD-aware block remap (each XCD chunk = 16 mt x 16 hu: W1T 4MB L2-resident,
// A-tiles L2-reused 16x), c folded into acc init, bV dropped (cancels in
// softmax). grid 2048 blocks (raw), block 512 (8 waves, 2Mx4N, 128x64/wave).
// ---------------------------------------------------------------------------
#define BKQ 32

__global__ __launch_bounds__(512, 2) void score_kernel(
    const u16* __restrict__ Abf, const u16* __restrict__ W1T,
    const float* __restrict__ C, const float* __restrict__ V,
    float* __restrict__ pscore) {
  // HW round-robins blockIdx.x across 8 XCDs; remap so each XCD gets a
  // contiguous logical chunk ordered mt-major / hu-minor.
  int bid = blockIdx.x;                       // 0..2047
  int logical = (bid & 7) * 256 + (bid >> 3);
  int mt = logical >> 4;                      // 0..127
  int hu = logical & 15;
  int h = hu & 7, ut = hu >> 3;
  int b = mt >> 3;                            // 8 l-chunks per batch entry
  int l0 = (mt & 7) * 256;
  int u0 = ut * 256;

  int tid = threadIdx.x;
  int lane = tid & 63, wid = tid >> 6;
  int wr = wid >> 2, wc = wid & 3;            // 2 x 4 waves; 128l x 64u each
  int rl = lane & 15, q = lane >> 4;

  __shared__ u16 As[4][256 * BKQ];            // 64 KB
  __shared__ u16 Bs[4][256 * BKQ];            // 64 KB
  __shared__ float redsm[4][256];             // 4 KB

  const u16* Fb = Abf + ((size_t)b * L_ + l0) * DF;
  const u16* Wh = W1T + ((size_t)h * U_ + u0) * DF;

  float cu[4], vv[4];
#pragma unroll
  for (int n = 0; n < 4; ++n) {
    int col = u0 + wc * 64 + n * 16 + rl;
    cu[n] = C[(size_t)(b * H_ + h) * U_ + col];
    vv[n] = V[h * U_ + col];
  }
  f32x4 acc[8][4];
#pragma unroll
  for (int m = 0; m < 8; ++m)
#pragma unroll
    for (int n = 0; n < 4; ++n)
#pragma unroll
      for (int j = 0; j < 4; ++j) acc[m][n][j] = cu[n];  // fold +c

  // Staging: per K-step 1024 16B-chunks per matrix, 2/thread each.
  // Physical chunk (row, ch) holds logical chunk ch ^ ((row>>1)&3)
  // (involution; same XOR on the read side -> conflict-free ds_read_b128).
#define STAGE(bufi, kb)                                                    \
  {                                                                        \
    _Pragma("unroll") for (int i_ = 0; i_ < 2; ++i_) {                     \
      int idx_ = i_ * 512 + tid;                                           \
      int row_ = idx_ >> 2;                                                \
      int ke_ = ((idx_ & 3) ^ ((row_ >> 1) & 3)) << 3;                     \
      load_lds16(Fb + ((size_t)row_ << 9) + (kb) + ke_,                    \
                 &As[bufi][idx_ * 8]);                                     \
    }                                                                      \
    _Pragma("unroll") for (int i_ = 0; i_ < 2; ++i_) {                     \
      int idx_ = i_ * 512 + tid;                                           \
      int row_ = idx_ >> 2;                                                \
      int ke_ = ((idx_ & 3) ^ ((row_ >> 1) & 3)) << 3;                     \
      load_lds16(Wh + ((size_t)row_ << 9) + (kb) + ke_,                    \
                 &Bs[bufi][idx_ * 8]);                                     \
    }                                                                      \
  }

#define COMPUTE(bufi)                                                      \
  {                                                                        \
    bf16x8 bF[4];                                                          \
    _Pragma("unroll") for (int n = 0; n < 4; ++n) {                        \
      int rB = wc * 64 + n * 16 + rl;                                      \
      bF[n] = *(const bf16x8*)&Bs[bufi][(rB << 5) +                        \
                                        ((q ^ ((rB >> 1) & 3)) << 3)];     \
    }                                                                      \
    _Pragma("unroll") for (int m = 0; m < 8; ++m) {                        \
      int rA = wr * 128 + m * 16 + rl;                                     \
      bf16x8 aF = *(const bf16x8*)&As[bufi][(rA << 5) +                    \
                                           ((q ^ ((rA >> 1) & 3)) << 3)];  \
      _Pragma("unroll") for (int n = 0; n < 4; ++n)                        \
        acc[m][n] = __builtin_amdgcn_mfma_f32_16x16x32_bf16(               \
            aF, bF[n], acc[m][n], 0, 0, 0);                                \
    }                                                                      \
  }

  // prologue: 3 K-steps staged ahead
  STAGE(0, 0);
  STAGE(1, BKQ);
  STAGE(2, 2 * BKQ);

#pragma unroll 1
  for (int t = 0; t < 13; ++t) {
    STAGE((t + 3) & 3, (t + 3) * BKQ);
    asm volatile("s_waitcnt vmcnt(12)" ::: "memory");  // stage(t) landed
    __builtin_amdgcn_s_barrier();
    COMPUTE(t & 3);
    asm volatile("s_waitcnt lgkmcnt(0)" ::: "memory");  // reads done
    __builtin_amdgcn_s_barrier();
  }
  // tail: t = 13, 14, 15 (no staging; drain counted)
  asm volatile("s_waitcnt vmcnt(8)" ::: "memory");
  __builtin_amdgcn_s_barrier();
  COMPUTE(1);
  asm volatile("s_waitcnt lgkmcnt(0)" ::: "memory");
  __builtin_amdgcn_s_barrier();
  asm volatile("s_waitcnt vmcnt(4)" ::: "memory");
  __builtin_amdgcn_s_barrier();
  COMPUTE(2);
  asm volatile("s_waitcnt lgkmcnt(0)" ::: "memory");
  __builtin_amdgcn_s_barrier();
  asm volatile("s_waitcnt vmcnt(0)" ::: "memory");
  __builtin_amdgcn_s_barrier();
  COMPUTE(3);
#undef STAGE
#undef COMPUTE

  // epilogue: tanh, *V, reduce over this block's 256-u slice
  float part[32];
#pragma unroll
  for (int m = 0; m < 8; ++m)
#pragma unroll
    for (int j = 0; j < 4; ++j) {
      float s = 0.f;
#pragma unroll
      for (int n = 0; n < 4; ++n) s += fast_tanh2(acc[m][n][j]) * vv[n];
      part[m * 4 + j] = s;
    }
#pragma unroll
  for (int p = 0; p < 32; ++p) {
    float v = part[p];
    v += __shfl_xor(v, 1, 64);
    v += __shfl_xor(v, 2, 64);
    v += __shfl_xor(v, 4, 64);
    v += __shfl_xor(v, 8, 64);
    part[p] = v;
  }
  __syncthreads();
  if (rl == 0) {
#pragma unroll
    for (int m = 0; m < 8; ++m)
#pragma unroll
      for (int j = 0; j < 4; ++j)
        redsm[wc][wr * 128 + m * 16 + q * 4 + j] = part[m * 4 + j];
  }
  __syncthreads();
  if (tid < 256) {
    float s = redsm[0][tid] + redsm[1][tid] + redsm[2][tid] + redsm[3][tid];
    pscore[((size_t)ut * B_ * H_ + b * H_ + h) * L_ + l0 + tid] = s;
  }
}

// ---------------------------------------------------------------------------
// softmax over L per (b,h): sums the 2 u-slice partial scores (bV omitted --
// uniform over L, cancels in softmax), writes attn + aw_out [B,L,H,1].
// ---------------------------------------------------------------------------
__global__ __launch_bounds__(256) void softmax_kernel(
    const float* __restrict__ pscore, float* __restrict__ attn,
    float* __restrict__ aw_out) {
  int bh = blockIdx.x;
  int b = bh / H_, h = bh % H_;
  const float* p0 = pscore + (size_t)bh * L_;
  const float* p1 = pscore + ((size_t)B_ * H_ + bh) * L_;
  __shared__ float sv[L_];  // 8 KB
  __shared__ float red[256];

  for (int i = threadIdx.x; i < L_ / 4; i += 256) {
    float4 a = ((const float4*)p0)[i];
    float4 c = ((const float4*)p1)[i];
    a.x += c.x; a.y += c.y; a.z += c.z; a.w += c.w;
    ((float4*)sv)[i] = a;
  }
  __syncthreads();

  float m = -1e30f;
  for (int l = threadIdx.x; l < L_; l += 256) m = fmaxf(m, sv[l]);
  red[threadIdx.x] = m;
  __syncthreads();
  for (int st = 128; st > 0; st >>= 1) {
    if (threadIdx.x < st)
      red[threadIdx.x] = fmaxf(red[threadIdx.x], red[threadIdx.x + st]);
    __syncthreads();
  }
  m = red[0];
  __syncthreads();

  float sum = 0.f;
  for (int l = threadIdx.x; l < L_; l += 256) sum += __expf(sv[l] - m);
  red[threadIdx.x] = sum;
  __syncthreads();
  for (int st = 128; st > 0; st >>= 1) {
    if (threadIdx.x < st) red[threadIdx.x] += red[threadIdx.x + st];
    __syncthreads();
  }
  float inv = 1.f / red[0];

  for (int l = threadIdx.x; l < L_; l += 256) {
    float a = __expf(sv[l] - m) * inv;
    attn[(size_t)bh * L_ + l] = a;
    aw_out[((size_t)b * L_ + l) * H_ + h] = a;
  }
}

// ---------------------------------------------------------------------------
// context split-L: partial[lz][b,h,d] = sum_{l in chunk lz} attn*F
// ---------------------------------------------------------------------------
__global__ __launch_bounds__(256) void context_part_kernel(
    const float* __restrict__ F, const float* __restrict__ attn,
    float* __restrict__ partial) {
  int b = blockIdx.x;
  int d0 = blockIdx.y * 64;
  int lz = blockIdx.z;
  int td = threadIdx.x & 63;
  int tl = threadIdx.x >> 6;  // 0..3

  __shared__ float as[H_][256];  // 8 KB
  for (int idx = threadIdx.x; idx < H_ * 256; idx += 256)
    as[idx >> 8][idx & 255] =
        attn[((size_t)b * H_ + (idx >> 8)) * L_ + lz * 256 + (idx & 255)];
  __syncthreads();

  float acc[H_] = {};
  for (int l = tl; l < 256; l += 4) {
    float f = F[((size_t)b * L_ + lz * 256 + l) * DF + d0 + td];
#pragma unroll
    for (int h = 0; h < H_; h++) acc[h] += as[h][l] * f;
  }

  __shared__ float red[4][H_][64];  // 8 KB
#pragma unroll
  for (int h = 0; h < H_; h++) red[tl][h][td] = acc[h];
  __syncthreads();
  if (tl == 0) {
#pragma unroll
    for (int h = 0; h < H_; h++) {
      float v = red[0][h][td] + red[1][h][td] + red[2][h][td] + red[3][h][td];
      partial[(size_t)lz * B_ * H_ * DF + ((size_t)b * H_ + h) * DF + d0 + td] =
          v;
    }
  }
}

__global__ __launch_bounds__(256) void context_combine_kernel(
    const float* __restrict__ partial, float* __restrict__ ctx_out) {
  int i = blockIdx.x * 256 + threadIdx.x;  // over B*H*DF
  float s = 0.f;
#pragma unroll
  for (int z = 0; z < 8; z++) s += partial[(size_t)z * B_ * H_ * DF + i];
  ctx_out[i] = s;
}

// ---------------------------------------------------------------------------
extern "C" void kernel_launch(void* const* d_in, const int* in_sizes, int n_in,
                              void* d_out, int out_size, void* d_ws,
                              size_t ws_size, hipStream_t stream) {
  const float* features = (const float*)d_in[0];  // [B,L,Df]
  const float* hidden   = (const float*)d_in[1];  // [B,H,Dh]
  const float* W1       = (const float*)d_in[2];  // [H,Df,U]
  const float* b1       = (const float*)d_in[3];  // [H,U]
  const float* W2       = (const float*)d_in[4];  // [H,Dh,U]
  const float* b2       = (const float*)d_in[5];  // [H,U]
  const float* V        = (const float*)d_in[6];  // [H,U]
  // d_in[7] = bV: uniform over L per (b,h) -> cancels in softmax; unused.

  float* out = (float*)d_out;
  float* ctx_out = out;                 // [B,H,Df]
  float* aw_out  = out + B_ * H_ * DF;  // [B,L,H,1]

  // ws layout (floats): c | pscore[2] | cpart, then bf16: Abf | W1T
  //  - hproj partials alias pscore: fully consumed by hproj_combine before
  //    score_kernel writes pscore.
  //  - attn aliases pscore slice 0 (softmax caches row in LDS before write).
  float* c_buf  = (float*)d_ws;
  float* pscore = c_buf + (size_t)B_ * H_ * U_;
  float* attn   = pscore;  // alias (see above)
  float* hpart  = pscore;  // alias (see above)
  float* cpart  = pscore + (size_t)2 * B_ * H_ * L_;  // 8*B*H*DF f
  u16* Abf = (u16*)(cpart + (size_t)8 * B_ * H_ * DF);
  u16* W1T = Abf + (size_t)B_ * L_ * DF;

  convert_kernel<<<16384 + 2048, 256, 0, stream>>>(features, Abf, W1, W1T);
  hproj_part_kernel<<<dim3(H_, U_ / 128, 8), 128, 0, stream>>>(hidden, W2,
                                                               hpart);
  hproj_combine_kernel<<<(B_ * H_ * U_) / 256, 256, 0, stream>>>(hpart, b1, b2,
                                                                 c_buf);
  score_kernel<<<2048, 512, 0, stream>>>(Abf, W1T, c_buf, V, pscore);
  softmax_kernel<<<B_ * H_, 256, 0, stream>>>(pscore, attn, aw_out);
  context_part_kernel<<<dim3(B_, DF / 64, 8), 256, 0, stream>>>(features, attn,
                                                                cpart);
  context_combine_kernel<<<(B_ * H_ * DF) / 256, 256, 0, stream>>>(cpart,
                                                                   ctx_out);
}

// Round 9
// 250.372 us; speedup vs baseline: 1.0733x; 1.0733x over previous
//
#include <hip/hip_runtime.h>
#include <hip/hip_bf16.h>

// Problem dims
#define B_ 16
#define L_ 2048
#define DF 512
#define H_ 8
#define DH 512
#define U_ 512

typedef unsigned short u16;
typedef __attribute__((ext_vector_type(8))) short bf16x8;
typedef __attribute__((ext_vector_type(4))) float f32x4;

__device__ __forceinline__ u16 f2bf(float x) {
  __hip_bfloat16 h = __float2bfloat16(x);
  u16 u;
  __builtin_memcpy(&u, &h, 2);
  return u;
}

__device__ __forceinline__ void load_lds16(const void* g, void* l) {
  __builtin_amdgcn_global_load_lds(
      (const __attribute__((address_space(1))) void*)g,
      (__attribute__((address_space(3))) void*)l, 16, 0, 0);
}

// tanh(x) = 1 - 2/(1+e^{2x}); exact at +-inf, ~1e-6 abs err.
__device__ __forceinline__ float fast_tanh2(float x) {
  float e = __expf(2.f * x);
  return 1.f - __fdividef(2.f, e + 1.f);
}

// ---------------------------------------------------------------------------
// Merged conversion kernel:
//  blocks [0, 16384): features fp32 -> bf16 [B,L,DF], 4 elems/thread
//  blocks [16384, 18432): W1 [H,DF,U] -> W1T [H,U,DF] bf16 (32x32 transpose)
// ---------------------------------------------------------------------------
__global__ __launch_bounds__(256) void convert_kernel(
    const float* __restrict__ F, u16* __restrict__ Abf,
    const float* __restrict__ W1, u16* __restrict__ W1T) {
  __shared__ float t[32][33];
  if (blockIdx.x < 16384) {
    size_t i = ((size_t)blockIdx.x * 256 + threadIdx.x) * 4;
    float4 v = *(const float4*)(F + i);
    ushort4 o;
    o.x = f2bf(v.x); o.y = f2bf(v.y); o.z = f2bf(v.z); o.w = f2bf(v.w);
    *(ushort4*)(Abf + i) = o;
  } else {
    int bid = blockIdx.x - 16384;
    int d0 = (bid & 15) * 32, u0 = ((bid >> 4) & 15) * 32, h = bid >> 8;
    const float* src = W1 + (size_t)h * DF * U_;
    u16* dst = W1T + (size_t)h * U_ * DF;
#pragma unroll
    for (int i = 0; i < 4; ++i) {
      int idx = threadIdx.x + i * 256;
      int r = idx >> 5, c = idx & 31;
      t[r][c] = src[(size_t)(d0 + r) * U_ + u0 + c];
    }
    __syncthreads();
#pragma unroll
    for (int i = 0; i < 4; ++i) {
      int idx = threadIdx.x + i * 256;
      int r = idx >> 5, c = idx & 31;  // r: u index, c: d index
      dst[(size_t)(u0 + r) * DF + d0 + c] = f2bf(t[c][r]);
    }
  }
}

// ---------------------------------------------------------------------------
// hproj split-d: partial[z,b,h,u] = sum_{d in chunk z} hidden*W2
// ---------------------------------------------------------------------------
__global__ __launch_bounds__(128) void hproj_part_kernel(
    const float* __restrict__ hidden, const float* __restrict__ W2,
    float* __restrict__ partial) {
  int h = blockIdx.x;
  int u = blockIdx.y * 128 + threadIdx.x;
  int d0 = blockIdx.z * 64;
  __shared__ float hs[B_][64];
  for (int idx = threadIdx.x; idx < B_ * 64; idx += 128) {
    int b = idx >> 6, d = idx & 63;
    hs[b][d] = hidden[(size_t)(b * H_ + h) * DH + d0 + d];
  }
  __syncthreads();
  float acc[B_];
#pragma unroll
  for (int b = 0; b < B_; b++) acc[b] = 0.f;
  const float* w2p = W2 + ((size_t)h * DH + d0) * U_ + u;
  for (int d = 0; d < 64; d++) {
    float w = w2p[(size_t)d * U_];
#pragma unroll
    for (int b = 0; b < B_; b++) acc[b] += hs[b][d] * w;
  }
#pragma unroll
  for (int b = 0; b < B_; b++)
    partial[(((size_t)blockIdx.z * B_ + b) * H_ + h) * U_ + u] = acc[b];
}

__global__ __launch_bounds__(256) void hproj_combine_kernel(
    const float* __restrict__ partial, const float* __restrict__ b1,
    const float* __restrict__ b2, float* __restrict__ c) {
  int i = blockIdx.x * 256 + threadIdx.x;  // over B*H*U
  int hu = i & (H_ * U_ - 1);
  float s = b1[hu] + b2[hu];
#pragma unroll
  for (int z = 0; z < 8; z++) s += partial[(size_t)z * B_ * H_ * U_ + i];
  c[i] = s;
}

// ---------------------------------------------------------------------------
// score kernel v9: 128(l) x 512(u) per block. Two live n-halves (acc[2][4][4])
// x 2 outer U-hops -> A restaged only 2x (total staged 1.6 GB vs R5's 2.1).
// BK=32, TRIPLE-buffered LDS (73 KB -> 2 blocks/CU) with counted vmcnt(12)
// (2-step issue->use distance), XOR swizzle (conflict-free, R4-verified),
// cu/vv preloaded per hop before the staging pipeline, c folded into acc,
// bV dropped (cancels in softmax), XCD-aware remap.
// grid 2048 (flat), block 256 (4 waves, 2wr x 2wc; wave = 64l x 64u per nh).
// ---------------------------------------------------------------------------
#define BKN 32

__global__ __launch_bounds__(256, 2) void score_kernel(
    const u16* __restrict__ Abf, const u16* __restrict__ W1T,
    const float* __restrict__ C, const float* __restrict__ V,
    float* __restrict__ score) {
  // XCD remap: 8 XCDs round-robin raw blockIdx; give each a contiguous
  // logical chunk (mt-major) so A-tiles and W1T stay L2-local.
  int bid = blockIdx.x;                       // 0..2047
  int logical = (bid & 7) * 256 + (bid >> 3);
  int mt = logical >> 3;                      // 0..255 : (b, l-tile)
  int h = logical & 7;
  int b = mt >> 4;
  int l0 = (mt & 15) * 128;

  int tid = threadIdx.x;
  int lane = tid & 63, wid = tid >> 6;
  int wr = wid >> 1, wc = wid & 1;            // 2 x 2 waves
  int rl = lane & 15, q = lane >> 4;

  __shared__ u16 As[3][128 * BKN];            // 8 KB each  -> 24 KB
  __shared__ u16 Bs[3][256 * BKN];            // 16 KB each -> 48 KB
  __shared__ float redsm[2][128];             // 1 KB

  const u16* Fb = Abf + ((size_t)b * L_ + l0) * DF;
  const u16* Wh = W1T + (size_t)h * U_ * DF;
  const float* Cb = C + (size_t)(b * H_ + h) * U_;
  const float* Vh = V + (size_t)h * U_;

  float part[16];
#pragma unroll
  for (int p = 0; p < 16; ++p) part[p] = 0.f;

  // Staging swizzle (BK=32: 4 chunks/row): phys chunk ch holds logical
  // ch ^ ((row>>1)&3); same XOR on the read side -> 2-way (free) LDS banks.
#define STAGE_A(bufi, kb)                                                  \
  {                                                                        \
    _Pragma("unroll") for (int i_ = 0; i_ < 2; ++i_) {                     \
      int idx_ = i_ * 256 + tid;                                           \
      int row_ = idx_ >> 2;                                                \
      int ke_ = ((idx_ & 3) ^ ((row_ >> 1) & 3)) << 3;                     \
      load_lds16(Fb + ((size_t)row_ << 9) + (kb) + ke_,                    \
                 &As[bufi][idx_ * 8]);                                     \
    }                                                                      \
  }
#define STAGE_B(bufi, kb, ubase)                                           \
  {                                                                        \
    _Pragma("unroll") for (int i_ = 0; i_ < 4; ++i_) {                     \
      int idx_ = i_ * 256 + tid;                                           \
      int row_ = idx_ >> 2;                                                \
      int ke_ = ((idx_ & 3) ^ ((row_ >> 1) & 3)) << 3;                     \
      load_lds16(Wh + (((size_t)(ubase) + row_) << 9) + (kb) + ke_,        \
                 &Bs[bufi][idx_ * 8]);                                     \
    }                                                                      \
  }

  f32x4 acc[2][4][4];

#define COMPUTE(bufi)                                                      \
  {                                                                        \
    bf16x8 aF[4], bF[2][4];                                                \
    _Pragma("unroll") for (int m = 0; m < 4; ++m) {                        \
      int rA = wr * 64 + m * 16 + rl;                                      \
      aF[m] = *(const bf16x8*)&As[bufi][(rA << 5) +                        \
                                        ((q ^ ((rA >> 1) & 3)) << 3)];     \
    }                                                                      \
    _Pragma("unroll") for (int nh = 0; nh < 2; ++nh)                       \
    _Pragma("unroll") for (int n = 0; n < 4; ++n) {                        \
      int rB = nh * 128 + wc * 64 + n * 16 + rl;                           \
      bF[nh][n] = *(const bf16x8*)&Bs[bufi][(rB << 5) +                    \
                                            ((q ^ ((rB >> 1) & 3)) << 3)]; \
    }                                                                      \
    _Pragma("unroll") for (int nh = 0; nh < 2; ++nh)                       \
    _Pragma("unroll") for (int m = 0; m < 4; ++m)                          \
    _Pragma("unroll") for (int n = 0; n < 4; ++n)                          \
      acc[nh][m][n] = __builtin_amdgcn_mfma_f32_16x16x32_bf16(             \
          aF[m], bF[nh][n], acc[nh][m][n], 0, 0, 0);                       \
  }

#pragma unroll 1
  for (int oc = 0; oc < 2; ++oc) {
    int ubase = oc * 256;
    // per-hop bias/V (plain loads; compiler drains them before acc init,
    // so the counted-vmcnt pipeline below starts from a clean baseline)
    float cu[2][4], vv[2][4];
#pragma unroll
    for (int nh = 0; nh < 2; ++nh)
#pragma unroll
      for (int n = 0; n < 4; ++n) {
        int col = ubase + nh * 128 + wc * 64 + n * 16 + rl;
        cu[nh][n] = Cb[col];
        vv[nh][n] = Vh[col];
      }
#pragma unroll
    for (int nh = 0; nh < 2; ++nh)
#pragma unroll
      for (int m = 0; m < 4; ++m)
#pragma unroll
        for (int n = 0; n < 4; ++n)
#pragma unroll
          for (int j = 0; j < 4; ++j) acc[nh][m][n][j] = cu[nh][n];

    // prologue: stage K-steps 0,1 into bufs 0,1
    STAGE_A(0, 0);
    STAGE_B(0, 0, ubase);
    STAGE_A(1, BKN);
    STAGE_B(1, BKN, ubase);

#pragma unroll 1
    for (int t = 0; t < 16; ++t) {
      int cur = t % 3;
      if (t < 14) {
        int nb = (t + 2) % 3;
        STAGE_A(nb, (t + 2) * BKN);
        STAGE_B(nb, (t + 2) * BKN, ubase);
        asm volatile("s_waitcnt vmcnt(12)" ::: "memory");  // stage(t) landed
      } else if (t == 14) {
        asm volatile("s_waitcnt vmcnt(6)" ::: "memory");
      } else {
        asm volatile("s_waitcnt vmcnt(0)" ::: "memory");
      }
      __builtin_amdgcn_s_barrier();
      __builtin_amdgcn_sched_barrier(0);
      __builtin_amdgcn_s_setprio(1);
      COMPUTE(cur);
      __builtin_amdgcn_s_setprio(0);
      asm volatile("s_waitcnt lgkmcnt(0)" ::: "memory");
      __builtin_amdgcn_sched_barrier(0);
      __builtin_amdgcn_s_barrier();
    }

    // hop epilogue: tanh, *V, accumulate per-row partials
#pragma unroll
    for (int nh = 0; nh < 2; ++nh)
#pragma unroll
      for (int m = 0; m < 4; ++m)
#pragma unroll
        for (int j = 0; j < 4; ++j) {
          float s = 0.f;
#pragma unroll
          for (int n = 0; n < 4; ++n)
            s += fast_tanh2(acc[nh][m][n][j]) * vv[nh][n];
          part[m * 4 + j] += s;
        }
  }
#undef STAGE_A
#undef STAGE_B
#undef COMPUTE

  // reduce over the 16 u-cols held per 16-lane group
#pragma unroll
  for (int p = 0; p < 16; ++p) {
    float v = part[p];
    v += __shfl_xor(v, 1, 64);
    v += __shfl_xor(v, 2, 64);
    v += __shfl_xor(v, 4, 64);
    v += __shfl_xor(v, 8, 64);
    part[p] = v;
  }
  __syncthreads();
  if (rl == 0) {
#pragma unroll
    for (int m = 0; m < 4; ++m)
#pragma unroll
      for (int j = 0; j < 4; ++j)
        redsm[wc][wr * 64 + m * 16 + q * 4 + j] = part[m * 4 + j];
  }
  __syncthreads();
  if (tid < 128) {
    float s = redsm[0][tid] + redsm[1][tid];
    score[(size_t)(b * H_ + h) * L_ + l0 + tid] = s;
  }
}

// ---------------------------------------------------------------------------
// softmax over L per (b,h) (bV omitted -- uniform over L, cancels);
// writes attn (aliases score -- row LDS-cached first) + aw_out [B,L,H,1].
// ---------------------------------------------------------------------------
__global__ __launch_bounds__(256) void softmax_kernel(
    const float* __restrict__ score, float* __restrict__ attn,
    float* __restrict__ aw_out) {
  int bh = blockIdx.x;
  int b = bh / H_, h = bh % H_;
  const float* s = score + (size_t)bh * L_;
  __shared__ float sv[L_];  // 8 KB
  __shared__ float red[256];

  for (int i = threadIdx.x; i < L_ / 4; i += 256)
    ((float4*)sv)[i] = ((const float4*)s)[i];
  __syncthreads();

  float m = -1e30f;
  for (int l = threadIdx.x; l < L_; l += 256) m = fmaxf(m, sv[l]);
  red[threadIdx.x] = m;
  __syncthreads();
  for (int st = 128; st > 0; st >>= 1) {
    if (threadIdx.x < st)
      red[threadIdx.x] = fmaxf(red[threadIdx.x], red[threadIdx.x + st]);
    __syncthreads();
  }
  m = red[0];
  __syncthreads();

  float sum = 0.f;
  for (int l = threadIdx.x; l < L_; l += 256) sum += __expf(sv[l] - m);
  red[threadIdx.x] = sum;
  __syncthreads();
  for (int st = 128; st > 0; st >>= 1) {
    if (threadIdx.x < st) red[threadIdx.x] += red[threadIdx.x + st];
    __syncthreads();
  }
  float inv = 1.f / red[0];

  for (int l = threadIdx.x; l < L_; l += 256) {
    float a = __expf(sv[l] - m) * inv;
    attn[(size_t)bh * L_ + l] = a;
    aw_out[((size_t)b * L_ + l) * H_ + h] = a;
  }
}

// ---------------------------------------------------------------------------
// context split-L: partial[lz][b,h,d] = sum_{l in chunk lz} attn*F
// ---------------------------------------------------------------------------
__global__ __launch_bounds__(256) void context_part_kernel(
    const float* __restrict__ F, const float* __restrict__ attn,
    float* __restrict__ partial) {
  int b = blockIdx.x;
  int d0 = blockIdx.y * 64;
  int lz = blockIdx.z;
  int td = threadIdx.x & 63;
  int tl = threadIdx.x >> 6;  // 0..3

  __shared__ float as[H_][256];  // 8 KB
  for (int idx = threadIdx.x; idx < H_ * 256; idx += 256)
    as[idx >> 8][idx & 255] =
        attn[((size_t)b * H_ + (idx >> 8)) * L_ + lz * 256 + (idx & 255)];
  __syncthreads();

  float acc[H_] = {};
  for (int l = tl; l < 256; l += 4) {
    float f = F[((size_t)b * L_ + lz * 256 + l) * DF + d0 + td];
#pragma unroll
    for (int h = 0; h < H_; h++) acc[h] += as[h][l] * f;
  }

  __shared__ float red[4][H_][64];  // 8 KB
#pragma unroll
  for (int h = 0; h < H_; h++) red[tl][h][td] = acc[h];
  __syncthreads();
  if (tl == 0) {
#pragma unroll
    for (int h = 0; h < H_; h++) {
      float v = red[0][h][td] + red[1][h][td] + red[2][h][td] + red[3][h][td];
      partial[(size_t)lz * B_ * H_ * DF + ((size_t)b * H_ + h) * DF + d0 + td] =
          v;
    }
  }
}

__global__ __launch_bounds__(256) void context_combine_kernel(
    const float* __restrict__ partial, float* __restrict__ ctx_out) {
  int i = blockIdx.x * 256 + threadIdx.x;  // over B*H*DF
  float s = 0.f;
#pragma unroll
  for (int z = 0; z < 8; z++) s += partial[(size_t)z * B_ * H_ * DF + i];
  ctx_out[i] = s;
}

// ---------------------------------------------------------------------------
extern "C" void kernel_launch(void* const* d_in, const int* in_sizes, int n_in,
                              void* d_out, int out_size, void* d_ws,
                              size_t ws_size, hipStream_t stream) {
  const float* features = (const float*)d_in[0];  // [B,L,Df]
  const float* hidden   = (const float*)d_in[1];  // [B,H,Dh]
  const float* W1       = (const float*)d_in[2];  // [H,Df,U]
  const float* b1       = (const float*)d_in[3];  // [H,U]
  const float* W2       = (const float*)d_in[4];  // [H,Dh,U]
  const float* b2       = (const float*)d_in[5];  // [H,U]
  const float* V        = (const float*)d_in[6];  // [H,U]
  // d_in[7] = bV: uniform over L per (b,h) -> cancels in softmax; unused.

  float* out = (float*)d_out;
  float* ctx_out = out;                 // [B,H,Df]
  float* aw_out  = out + B_ * H_ * DF;  // [B,L,H,1]

  // ws layout (floats): c | score | cpart, then bf16: Abf | W1T
  //  - hproj partials (524288 f) alias score+cpart (786432 f): consumed by
  //    hproj_combine before score/cpart are written.
  //  - attn aliases score (softmax LDS-caches the row before overwriting).
  float* c_buf = (float*)d_ws;
  float* score = c_buf + (size_t)B_ * H_ * U_;
  float* attn  = score;                              // alias (see above)
  float* hpart = score;                              // alias (see above)
  float* cpart = score + (size_t)B_ * H_ * L_;       // 8*B*H*DF floats
  u16* Abf = (u16*)(cpart + (size_t)8 * B_ * H_ * DF);
  u16* W1T = Abf + (size_t)B_ * L_ * DF;

  convert_kernel<<<16384 + 2048, 256, 0, stream>>>(features, Abf, W1, W1T);
  hproj_part_kernel<<<dim3(H_, U_ / 128, 8), 128, 0, stream>>>(hidden, W2,
                                                               hpart);
  hproj_combine_kernel<<<(B_ * H_ * U_) / 256, 256, 0, stream>>>(hpart, b1, b2,
                                                                 c_buf);
  score_kernel<<<2048, 256, 0, stream>>>(Abf, W1T, c_buf, V, score);
  softmax_kernel<<<B_ * H_, 256, 0, stream>>>(score, attn, aw_out);
  context_part_kernel<<<dim3(B_, DF / 64, 8), 256, 0, stream>>>(features, attn,
                                                                cpart);
  context_combine_kernel<<<(B_ * H_ * DF) / 256, 256, 0, stream>>>(cpart,
                                                                   ctx_out);
}

// Round 10
// 240.469 us; speedup vs baseline: 1.1175x; 1.0412x over previous
//
#include <hip/hip_runtime.h>
#include <hip/hip_bf16.h>

// Problem dims
#define B_ 16
#define L_ 2048
#define DF 512
#define H_ 8
#define DH 512
#define U_ 512

typedef unsigned short u16;
typedef __attribute__((ext_vector_type(8))) short bf16x8;
typedef __attribute__((ext_vector_type(4))) float f32x4;

__device__ __forceinline__ u16 f2bf(float x) {
  __hip_bfloat16 h = __float2bfloat16(x);
  u16 u;
  __builtin_memcpy(&u, &h, 2);
  return u;
}

__device__ __forceinline__ void load_lds16(const void* g, void* l) {
  __builtin_amdgcn_global_load_lds(
      (const __attribute__((address_space(1))) void*)g,
      (__attribute__((address_space(3))) void*)l, 16, 0, 0);
}

// tanh(x) = 1 - 2/(1+e^{2x}); exact at +-inf, ~1e-6 abs err.
__device__ __forceinline__ float fast_tanh2(float x) {
  float e = __expf(2.f * x);
  return 1.f - __fdividef(2.f, e + 1.f);
}

// ---------------------------------------------------------------------------
// Merged prep kernel:
//  blocks [0, 16384): features fp32 -> bf16 [B,L,DF], 4 elems/thread
//  blocks [16384, 18432): W1 [H,DF,U] -> W1T [H,U,DF] bf16 (32x32 transpose)
//  blocks [18432, 18560): hproj split-d partials (z = d-chunk of 64)
// ---------------------------------------------------------------------------
__global__ __launch_bounds__(256) void prep_kernel(
    const float* __restrict__ F, u16* __restrict__ Abf,
    const float* __restrict__ W1, u16* __restrict__ W1T,
    const float* __restrict__ hidden, const float* __restrict__ W2,
    float* __restrict__ hpart) {
  __shared__ float t[32][33];
  __shared__ float hs[B_][64];
  if (blockIdx.x < 16384) {
    size_t i = ((size_t)blockIdx.x * 256 + threadIdx.x) * 4;
    float4 v = *(const float4*)(F + i);
    ushort4 o;
    o.x = f2bf(v.x); o.y = f2bf(v.y); o.z = f2bf(v.z); o.w = f2bf(v.w);
    *(ushort4*)(Abf + i) = o;
  } else if (blockIdx.x < 18432) {
    int bid = blockIdx.x - 16384;
    int d0 = (bid & 15) * 32, u0 = ((bid >> 4) & 15) * 32, h = bid >> 8;
    const float* src = W1 + (size_t)h * DF * U_;
    u16* dst = W1T + (size_t)h * U_ * DF;
#pragma unroll
    for (int i = 0; i < 4; ++i) {
      int idx = threadIdx.x + i * 256;
      int r = idx >> 5, c = idx & 31;
      t[r][c] = src[(size_t)(d0 + r) * U_ + u0 + c];
    }
    __syncthreads();
#pragma unroll
    for (int i = 0; i < 4; ++i) {
      int idx = threadIdx.x + i * 256;
      int r = idx >> 5, c = idx & 31;  // r: u index, c: d index
      dst[(size_t)(u0 + r) * DF + d0 + c] = f2bf(t[c][r]);
    }
  } else {
    // hproj partial: 128 blocks = 8 h x 2 uy x 8 dz; 256 threads own one u
    int bid = blockIdx.x - 18432;
    int h = bid & 7, uy = (bid >> 3) & 1, dz = bid >> 4;
    int u = uy * 256 + threadIdx.x;
    int d0 = dz * 64;
    for (int idx = threadIdx.x; idx < B_ * 64; idx += 256) {
      int b = idx >> 6, d = idx & 63;
      hs[b][d] = hidden[(size_t)(b * H_ + h) * DH + d0 + d];
    }
    __syncthreads();
    float acc[B_];
#pragma unroll
    for (int b = 0; b < B_; b++) acc[b] = 0.f;
    const float* w2p = W2 + ((size_t)h * DH + d0) * U_ + u;
    for (int d = 0; d < 64; d++) {
      float w = w2p[(size_t)d * U_];
#pragma unroll
      for (int b = 0; b < B_; b++) acc[b] += hs[b][d] * w;
    }
#pragma unroll
    for (int b = 0; b < B_; b++)
      hpart[(((size_t)dz * B_ + b) * H_ + h) * U_ + u] = acc[b];
  }
}

__global__ __launch_bounds__(256) void hproj_combine_kernel(
    const float* __restrict__ partial, const float* __restrict__ b1,
    const float* __restrict__ b2, float* __restrict__ c) {
  int i = blockIdx.x * 256 + threadIdx.x;  // over B*H*U
  int hu = i & (H_ * U_ - 1);
  float s = b1[hu] + b2[hu];
#pragma unroll
  for (int z = 0; z < 8; z++) s += partial[(size_t)z * B_ * H_ * U_ + i];
  c[i] = s;
}

// ---------------------------------------------------------------------------
// score kernel v10 (= R5 schedule at 2x occupancy):
// 128x128 tile, nc=4 over U, BK=64 double-buffer (65 KB LDS), counted-vmcnt
// (vmcnt(4): one STAGE in flight across the barrier), verified XOR swizzle,
// c folded into acc init. EIGHT waves (2wr x 4wc), wave tile 64l x 32u ->
// acc 32 regs, VGPR ~100: __launch_bounds__(512,4) => 4 waves/SIMD (16/CU),
// double R5's occupancy at the cost of +50% LDS reads (not the binder).
// grid (L/128, B, H), block 512.
// ---------------------------------------------------------------------------
#define BKS 64

__global__ __launch_bounds__(512, 4) void score_kernel(
    const u16* __restrict__ Abf, const u16* __restrict__ W1T,
    const float* __restrict__ C, const float* __restrict__ V,
    float* __restrict__ score) {
  int l0 = blockIdx.x * 128;
  int b = blockIdx.y, h = blockIdx.z;
  int tid = threadIdx.x;
  int lane = tid & 63, wid = tid >> 6;
  int wr = wid >> 2, wc = wid & 3;  // 2 x 4 waves; wave = 64l x 32u
  int rl = lane & 15;
  int q = lane >> 4;
  int khalf = q << 3;  // bf16 elem offset of this quad's 16B

  __shared__ u16 As[2][128 * BKS];  // 16 KB each
  __shared__ u16 Bs[2][128 * BKS];
  __shared__ float redsm[4][128];   // 2 KB

  const u16* Fb = Abf + (size_t)b * L_ * DF;
  const u16* Wh = W1T + (size_t)h * U_ * DF;
  const float* Cb = C + (size_t)(b * H_ + h) * U_;
  const float* Vh = V + (size_t)h * U_;

  float part[16];
#pragma unroll
  for (int p = 0; p < 16; ++p) part[p] = 0.f;

  // Per matrix per K-step: 1024 16B-chunks; physical chunk (row, ch) holds
  // logical k-chunk ch ^ (row&7)  (involution; same XOR on the read side).
  // 512 threads -> 2 chunks per thread per matrix (4 loads/thread total).
#define STAGE(buf, kbase)                                                  \
  {                                                                        \
    _Pragma("unroll") for (int i_ = 0; i_ < 2; ++i_) {                     \
      int idx_ = i_ * 512 + tid;                                           \
      int row_ = idx_ >> 3;                                                \
      int ke_ = ((idx_ & 7) ^ (row_ & 7)) << 3;                            \
      load_lds16(Fb + (((size_t)(l0 + row_)) << 9) + (kbase) + ke_,        \
                 &As[buf][idx_ * 8]);                                      \
      load_lds16(Wh + (((size_t)(N0 + row_)) << 9) + (kbase) + ke_,        \
                 &Bs[buf][idx_ * 8]);                                      \
    }                                                                      \
  }

  for (int nc = 0; nc < 4; ++nc) {
    int N0 = nc * 128;
    // per-column h-proj bias and V weight for this wave's 32-u slice
    float cu[2], vv[2];
#pragma unroll
    for (int n = 0; n < 2; ++n) {
      int col = N0 + wc * 32 + n * 16 + rl;
      cu[n] = Cb[col];
      vv[n] = Vh[col];
    }
    f32x4 acc[4][2];
#pragma unroll
    for (int m = 0; m < 4; ++m)
#pragma unroll
      for (int n = 0; n < 2; ++n)
#pragma unroll
        for (int j = 0; j < 4; ++j) acc[m][n][j] = cu[n];  // fold +c

    STAGE(0, 0);
    int cur = 0;
    for (int kt = 0; kt < 8; ++kt) {
      if (kt < 7) {
        STAGE(cur ^ 1, (kt + 1) * BKS);
        asm volatile("s_waitcnt vmcnt(4)" ::: "memory");
      } else {
        asm volatile("s_waitcnt vmcnt(0)" ::: "memory");
      }
      __builtin_amdgcn_s_barrier();
#pragma unroll
      for (int s = 0; s < 2; ++s) {
        bf16x8 bfr[2];
#pragma unroll
        for (int n = 0; n < 2; ++n) {
          int rB = wc * 32 + n * 16 + rl;
          bfr[n] = *(const bf16x8*)&Bs[cur][(rB << 6) +
                                            ((s * 32 + khalf) ^
                                             ((rB & 7) << 3))];
        }
#pragma unroll
        for (int m = 0; m < 4; ++m) {
          int rA = wr * 64 + m * 16 + rl;
          bf16x8 af = *(const bf16x8*)&As[cur][(rA << 6) +
                                               ((s * 32 + khalf) ^
                                                ((rA & 7) << 3))];
#pragma unroll
          for (int n = 0; n < 2; ++n)
            acc[m][n] = __builtin_amdgcn_mfma_f32_16x16x32_bf16(
                af, bfr[n], acc[m][n], 0, 0, 0);
        }
      }
      // this wave's LDS reads must complete before signaling next overwrite
      asm volatile("s_waitcnt lgkmcnt(0)" ::: "memory");
      __builtin_amdgcn_s_barrier();
      cur ^= 1;
    }
    // epilogue: tanh, *V, accumulate per-row partials
#pragma unroll
    for (int n = 0; n < 2; ++n)
#pragma unroll
      for (int m = 0; m < 4; ++m)
#pragma unroll
        for (int j = 0; j < 4; ++j)
          part[m * 4 + j] += fast_tanh2(acc[m][n][j]) * vv[n];
  }
#undef STAGE

  // reduce over the 16 u-cols held per 16-lane group (rl)
#pragma unroll
  for (int p = 0; p < 16; ++p) {
    float v = part[p];
    v += __shfl_xor(v, 1, 64);
    v += __shfl_xor(v, 2, 64);
    v += __shfl_xor(v, 4, 64);
    v += __shfl_xor(v, 8, 64);
    part[p] = v;
  }
  __syncthreads();
  if (rl == 0) {
#pragma unroll
    for (int m = 0; m < 4; ++m)
#pragma unroll
      for (int j = 0; j < 4; ++j)
        redsm[wc][wr * 64 + m * 16 + q * 4 + j] = part[m * 4 + j];
  }
  __syncthreads();
  if (tid < 128) {
    float s = redsm[0][tid] + redsm[1][tid] + redsm[2][tid] + redsm[3][tid];
    score[(size_t)(b * H_ + h) * L_ + l0 + tid] = s;
  }
}

// ---------------------------------------------------------------------------
// softmax over L per (b,h) (bV omitted -- uniform over L, cancels);
// writes attn (aliases score -- row LDS-cached first) + aw_out [B,L,H,1].
// ---------------------------------------------------------------------------
__global__ __launch_bounds__(256) void softmax_kernel(
    const float* __restrict__ score, float* __restrict__ attn,
    float* __restrict__ aw_out) {
  int bh = blockIdx.x;
  int b = bh / H_, h = bh % H_;
  const float* s = score + (size_t)bh * L_;
  __shared__ float sv[L_];  // 8 KB
  __shared__ float red[256];

  for (int i = threadIdx.x; i < L_ / 4; i += 256)
    ((float4*)sv)[i] = ((const float4*)s)[i];
  __syncthreads();

  float m = -1e30f;
  for (int l = threadIdx.x; l < L_; l += 256) m = fmaxf(m, sv[l]);
  red[threadIdx.x] = m;
  __syncthreads();
  for (int st = 128; st > 0; st >>= 1) {
    if (threadIdx.x < st)
      red[threadIdx.x] = fmaxf(red[threadIdx.x], red[threadIdx.x + st]);
    __syncthreads();
  }
  m = red[0];
  __syncthreads();

  float sum = 0.f;
  for (int l = threadIdx.x; l < L_; l += 256) sum += __expf(sv[l] - m);
  red[threadIdx.x] = sum;
  __syncthreads();
  for (int st = 128; st > 0; st >>= 1) {
    if (threadIdx.x < st) red[threadIdx.x] += red[threadIdx.x + st];
    __syncthreads();
  }
  float inv = 1.f / red[0];

  for (int l = threadIdx.x; l < L_; l += 256) {
    float a = __expf(sv[l] - m) * inv;
    attn[(size_t)bh * L_ + l] = a;
    aw_out[((size_t)b * L_ + l) * H_ + h] = a;
  }
}

// ---------------------------------------------------------------------------
// context split-L: partial[lz][b,h,d] = sum_{l in chunk lz} attn*F
// ---------------------------------------------------------------------------
__global__ __launch_bounds__(256) void context_part_kernel(
    const float* __restrict__ F, const float* __restrict__ attn,
    float* __restrict__ partial) {
  int b = blockIdx.x;
  int d0 = blockIdx.y * 64;
  int lz = blockIdx.z;
  int td = threadIdx.x & 63;
  int tl = threadIdx.x >> 6;  // 0..3

  __shared__ float as[H_][256];  // 8 KB
  for (int idx = threadIdx.x; idx < H_ * 256; idx += 256)
    as[idx >> 8][idx & 255] =
        attn[((size_t)b * H_ + (idx >> 8)) * L_ + lz * 256 + (idx & 255)];
  __syncthreads();

  float acc[H_] = {};
  for (int l = tl; l < 256; l += 4) {
    float f = F[((size_t)b * L_ + lz * 256 + l) * DF + d0 + td];
#pragma unroll
    for (int h = 0; h < H_; h++) acc[h] += as[h][l] * f;
  }

  __shared__ float red[4][H_][64];  // 8 KB
#pragma unroll
  for (int h = 0; h < H_; h++) red[tl][h][td] = acc[h];
  __syncthreads();
  if (tl == 0) {
#pragma unroll
    for (int h = 0; h < H_; h++) {
      float v = red[0][h][td] + red[1][h][td] + red[2][h][td] + red[3][h][td];
      partial[(size_t)lz * B_ * H_ * DF + ((size_t)b * H_ + h) * DF + d0 + td] =
          v;
    }
  }
}

__global__ __launch_bounds__(256) void context_combine_kernel(
    const float* __restrict__ partial, float* __restrict__ ctx_out) {
  int i = blockIdx.x * 256 + threadIdx.x;  // over B*H*DF
  float s = 0.f;
#pragma unroll
  for (int z = 0; z < 8; z++) s += partial[(size_t)z * B_ * H_ * DF + i];
  ctx_out[i] = s;
}

// ---------------------------------------------------------------------------
extern "C" void kernel_launch(void* const* d_in, const int* in_sizes, int n_in,
                              void* d_out, int out_size, void* d_ws,
                              size_t ws_size, hipStream_t stream) {
  const float* features = (const float*)d_in[0];  // [B,L,Df]
  const float* hidden   = (const float*)d_in[1];  // [B,H,Dh]
  const float* W1       = (const float*)d_in[2];  // [H,Df,U]
  const float* b1       = (const float*)d_in[3];  // [H,U]
  const float* W2       = (const float*)d_in[4];  // [H,Dh,U]
  const float* b2       = (const float*)d_in[5];  // [H,U]
  const float* V        = (const float*)d_in[6];  // [H,U]
  // d_in[7] = bV: uniform over L per (b,h) -> cancels in softmax; unused.

  float* out = (float*)d_out;
  float* ctx_out = out;                 // [B,H,Df]
  float* aw_out  = out + B_ * H_ * DF;  // [B,L,H,1]

  // ws layout (floats): c | score | cpart, then bf16: Abf | W1T
  //  - hproj partials (524288 f) alias score+cpart (786432 f): consumed by
  //    hproj_combine before score/cpart are written.
  //  - attn aliases score (softmax LDS-caches the row before overwriting).
  float* c_buf = (float*)d_ws;
  float* score = c_buf + (size_t)B_ * H_ * U_;
  float* attn  = score;                              // alias (see above)
  float* hpart = score;                              // alias (see above)
  float* cpart = score + (size_t)B_ * H_ * L_;       // 8*B*H*DF floats
  u16* Abf = (u16*)(cpart + (size_t)8 * B_ * H_ * DF);
  u16* W1T = Abf + (size_t)B_ * L_ * DF;

  prep_kernel<<<16384 + 2048 + 128, 256, 0, stream>>>(features, Abf, W1, W1T,
                                                      hidden, W2, hpart);
  hproj_combine_kernel<<<(B_ * H_ * U_) / 256, 256, 0, stream>>>(hpart, b1, b2,
                                                                 c_buf);
  score_kernel<<<dim3(L_ / 128, B_, H_), 512, 0, stream>>>(Abf, W1T, c_buf, V,
                                                           score);
  softmax_kernel<<<B_ * H_, 256, 0, stream>>>(score, attn, aw_out);
  context_part_kernel<<<dim3(B_, DF / 64, 8), 256, 0, stream>>>(features, attn,
                                                                cpart);
  context_combine_kernel<<<(B_ * H_ * DF) / 256, 256, 0, stream>>>(cpart,
                                                                   ctx_out);
}